// Round 1
// baseline (192.023 us; speedup 1.0000x reference)
//
#include <hip/hip_runtime.h>

typedef __attribute__((ext_vector_type(8))) short bf16x8;
typedef __attribute__((ext_vector_type(4))) float f32x4;

#define SZQKV 12582912  // B*N*C = one (q|k|v) output block, elements

__device__ __forceinline__ unsigned short f2bf(float f) {
    unsigned int u = __float_as_uint(f);
    unsigned int r = (u + 0x7FFFu + ((u >> 16) & 1u)) >> 16;
    return (unsigned short)r;
}

#define GLDS16(g, l) __builtin_amdgcn_global_load_lds( \
    (const __attribute__((address_space(1))) unsigned int*)(g), \
    (__attribute__((address_space(3))) unsigned int*)(l), 16, 0, 0)

// ---------------- cast f32 -> bf16 into workspace ----------------
__global__ void cast_all(const float* __restrict__ x,
                         const float* __restrict__ wqkv,
                         const float* __restrict__ wproj,
                         unsigned short* __restrict__ dst) {
    const int T1 = 12582912;       // x
    const int T2 = T1 + 1769472;   // + w_qkv
    const int T3 = T2 + 589824;    // + w_proj
    int stride = gridDim.x * blockDim.x * 4;
    for (int base = (blockIdx.x * blockDim.x + threadIdx.x) * 4; base < T3; base += stride) {
        const float* src; int off;
        if (base < T1)      { src = x;     off = base; }
        else if (base < T2) { src = wqkv;  off = base - T1; }
        else                { src = wproj; off = base - T2; }
        float4 v = *(const float4*)(src + off);
        ushort4 o;
        o.x = f2bf(v.x); o.y = f2bf(v.y); o.z = f2bf(v.z); o.w = f2bf(v.w);
        *(ushort4*)(dst + base) = o;
    }
}

// ---------------- GEMM1: qkv = x @ w_qkv^T, scatter to d_out ----------------
// A: [16384][768] bf16, Bw: [2304][768] bf16, out: q/k/v f32 blocks in d_out
__global__ __launch_bounds__(256) void gemm_qkv(const unsigned short* __restrict__ A,
                                                const unsigned short* __restrict__ Bw,
                                                float* __restrict__ dout) {
    __shared__ unsigned short lA[128 * 32];
    __shared__ unsigned short lB[128 * 32];
    const int m0 = blockIdx.x * 128;
    const int n0 = blockIdx.y * 128;
    const int t = threadIdx.x;
    const int lane = t & 63;
    const int w = t >> 6;
    const int wm = w >> 1, wn = w & 1;
    f32x4 acc[4][4] = {};

    for (int k0 = 0; k0 < 768; k0 += 32) {
#pragma unroll
        for (int i = 0; i < 2; ++i) {
            int elt = (i * 256 + t) * 8;
            int row = elt >> 5;   // /32
            int kk  = elt & 31;
            GLDS16(A  + (size_t)(m0 + row) * 768 + k0 + kk, &lA[elt]);
            GLDS16(Bw + (size_t)(n0 + row) * 768 + k0 + kk, &lB[elt]);
        }
        __syncthreads();
        bf16x8 av[4], bv[4];
#pragma unroll
        for (int mi = 0; mi < 4; ++mi)
            av[mi] = *(const bf16x8*)&lA[(wm * 64 + mi * 16 + (lane & 15)) * 32 + (lane >> 4) * 8];
#pragma unroll
        for (int ni = 0; ni < 4; ++ni)
            bv[ni] = *(const bf16x8*)&lB[(wn * 64 + ni * 16 + (lane & 15)) * 32 + (lane >> 4) * 8];
#pragma unroll
        for (int mi = 0; mi < 4; ++mi)
#pragma unroll
            for (int ni = 0; ni < 4; ++ni)
                acc[mi][ni] = __builtin_amdgcn_mfma_f32_16x16x32_bf16(av[mi], bv[ni], acc[mi][ni], 0, 0, 0);
        __syncthreads();
    }

    const int crow = (lane >> 4) * 4;  // + r -> C row
    const int ccol = lane & 15;        // C col
    const int b = m0 >> 12;            // 32 m-blocks per batch
    const int n_base = m0 & 4095;
#pragma unroll
    for (int mi = 0; mi < 4; ++mi) {
        int n = n_base + wm * 64 + mi * 16 + crow;  // 4 consecutive n (r=0..3)
#pragma unroll
        for (int ni = 0; ni < 4; ++ni) {
            int o = n0 + wn * 64 + ni * 16 + ccol;  // column in [0,2304)
            int sel = o / 768;                      // 0=q 1=k 2=v
            int rem = o - sel * 768;                // dil*256 + c'
            float* dst = dout + (size_t)(3 - sel) * SZQKV
                       + ((size_t)((rem >> 8) * 4 + b) * 256 + (rem & 255)) * 4096 + n;
            *(f32x4*)dst = acc[mi][ni];
        }
    }
}

// ---------------- attention: read q/k/v f32 from d_out, write bf16 [b][n][c] ----------------
__global__ __launch_bounds__(256) void attn_kernel(const float* __restrict__ qkv,
                                                   unsigned short* __restrict__ attnbf) {
    const int chunk = blockIdx.x;  // 64 chunks of 64 n
    const int dil_i = blockIdx.y;  // 0..2
    const int b     = blockIdx.z;  // 0..3
    const int dil   = dil_i + 1;
    const int t  = threadIdx.x;
    const int h  = t >> 6;         // wave = head
    const int nl = t & 63;
    const int n  = chunk * 64 + nl;

    const size_t gb = (size_t)(dil_i * 4 + b) * 256 * 4096;
    const float* Q = qkv + (size_t)3 * SZQKV + gb;
    const float* K = qkv + (size_t)2 * SZQKV + gb;
    const float* V = qkv + (size_t)1 * SZQKV + gb;

    const int nm = n - dil, np = n + dil;
    const bool vm = (nm >= 0), vp = (np < 4096);
    const int nmc = vm ? nm : 0, npc = vp ? np : 4095;

    float s0 = 0.f, s1 = 0.f, s2 = 0.f;
    {
        const float* qrow = Q + (size_t)h * 64 * 4096;
        const float* krow = K + (size_t)h * 64 * 4096;
        for (int d = 0; d < 64; ++d) {
            float q = qrow[n];
            s0 += q * krow[nmc];
            s1 += q * krow[n];
            s2 += q * krow[npc];
            qrow += 4096; krow += 4096;
        }
    }
    s0 = vm ? s0 * 0.125f : 0.f;   // padded K-column -> exact 0 score (matches ref)
    s1 *= 0.125f;
    s2 = vp ? s2 * 0.125f : 0.f;
    float mx = fmaxf(0.f, fmaxf(s0, fmaxf(s1, s2)));
    float e0 = __expf(s0 - mx), e1 = __expf(s1 - mx), e2 = __expf(s2 - mx);
    // softmax over 9 slots: 6 structural zeros contribute 6*exp(-mx)
    float den = e0 + e1 + e2 + 6.f * __expf(-mx);
    float inv = 1.f / den;
    float p0 = vm ? e0 * inv : 0.f;
    float p1 = e1 * inv;
    float p2 = vp ? e2 * inv : 0.f;

    __shared__ unsigned short lout[256][65];  // [c'][n] bf16, padded row
    {
        const float* vrow = V + (size_t)h * 64 * 4096;
        for (int d = 0; d < 64; ++d) {
            float o = p0 * vrow[nmc] + p1 * vrow[n] + p2 * vrow[npc];
            lout[h * 64 + d][nl] = f2bf(o);
            vrow += 4096;
        }
    }
    __syncthreads();

    // write tile transposed: attnbf[(b*4096+n)*768 + dil_i*256 + c], c fastest
#pragma unroll
    for (int i = 0; i < 8; ++i) {
        int linear = i * 256 + t;   // 0..2047
        int nn   = linear >> 5;     // 0..63
        int cblk = linear & 31;     // 0..31 (8 channels each)
        union { unsigned short u[8]; f32x4 v; } tt;
#pragma unroll
        for (int j = 0; j < 8; ++j) tt.u[j] = lout[cblk * 8 + j][nn];
        unsigned short* dst = attnbf + (size_t)(b * 4096 + chunk * 64 + nn) * 768
                            + dil_i * 256 + cblk * 8;
        *(f32x4*)dst = tt.v;
    }
}

// ---------------- GEMM2: xo = attn @ w_proj^T + b_proj ----------------
__global__ __launch_bounds__(256) void gemm_proj(const unsigned short* __restrict__ A,
                                                 const unsigned short* __restrict__ Bw,
                                                 const float* __restrict__ bias,
                                                 float* __restrict__ out) {
    __shared__ unsigned short lA[128 * 32];
    __shared__ unsigned short lB[128 * 32];
    const int m0 = blockIdx.x * 128;
    const int n0 = blockIdx.y * 128;
    const int t = threadIdx.x;
    const int lane = t & 63;
    const int w = t >> 6;
    const int wm = w >> 1, wn = w & 1;
    f32x4 acc[4][4] = {};

    for (int k0 = 0; k0 < 768; k0 += 32) {
#pragma unroll
        for (int i = 0; i < 2; ++i) {
            int elt = (i * 256 + t) * 8;
            int row = elt >> 5;
            int kk  = elt & 31;
            GLDS16(A  + (size_t)(m0 + row) * 768 + k0 + kk, &lA[elt]);
            GLDS16(Bw + (size_t)(n0 + row) * 768 + k0 + kk, &lB[elt]);
        }
        __syncthreads();
        bf16x8 av[4], bv[4];
#pragma unroll
        for (int mi = 0; mi < 4; ++mi)
            av[mi] = *(const bf16x8*)&lA[(wm * 64 + mi * 16 + (lane & 15)) * 32 + (lane >> 4) * 8];
#pragma unroll
        for (int ni = 0; ni < 4; ++ni)
            bv[ni] = *(const bf16x8*)&lB[(wn * 64 + ni * 16 + (lane & 15)) * 32 + (lane >> 4) * 8];
#pragma unroll
        for (int mi = 0; mi < 4; ++mi)
#pragma unroll
            for (int ni = 0; ni < 4; ++ni)
                acc[mi][ni] = __builtin_amdgcn_mfma_f32_16x16x32_bf16(av[mi], bv[ni], acc[mi][ni], 0, 0, 0);
        __syncthreads();
    }

    const int crow = (lane >> 4) * 4;
    const int ccol = lane & 15;
#pragma unroll
    for (int mi = 0; mi < 4; ++mi) {
        int m = m0 + wm * 64 + mi * 16 + crow;
#pragma unroll
        for (int ni = 0; ni < 4; ++ni) {
            int o = n0 + wn * 64 + ni * 16 + ccol;
            float bb = bias[o];
#pragma unroll
            for (int r = 0; r < 4; ++r)
                out[(size_t)(m + r) * 768 + o] = acc[mi][ni][r] + bb;
        }
    }
}

extern "C" void kernel_launch(void* const* d_in, const int* in_sizes, int n_in,
                              void* d_out, int out_size, void* d_ws, size_t ws_size,
                              hipStream_t stream) {
    const float* x     = (const float*)d_in[0];
    const float* wqkv  = (const float*)d_in[1];
    const float* wproj = (const float*)d_in[2];
    const float* bproj = (const float*)d_in[3];
    float* out = (float*)d_out;

    unsigned short* xbf     = (unsigned short*)d_ws;          // 12582912
    unsigned short* wqkvbf  = xbf + 12582912;                 // 1769472
    unsigned short* wprojbf = wqkvbf + 1769472;               // 589824
    unsigned short* attnbf  = wprojbf + 589824;               // 12582912

    cast_all<<<2048, 256, 0, stream>>>(x, wqkv, wproj, xbf);

    dim3 g1(128, 18);
    gemm_qkv<<<g1, 256, 0, stream>>>(xbf, wqkvbf, out);

    attn_kernel<<<dim3(64, 3, 4), 256, 0, stream>>>(out, attnbf);

    dim3 g2(128, 6);
    gemm_proj<<<g2, 256, 0, stream>>>(attnbf, wprojbf, bproj, out);
}

// Round 2
// 173.000 us; speedup vs baseline: 1.1100x; 1.1100x over previous
//
#include <hip/hip_runtime.h>

typedef __attribute__((ext_vector_type(8))) short bf16x8;
typedef __attribute__((ext_vector_type(4))) float f32x4;

#define SZQKV 12582912  // B*N*C = one (q|k|v) output block, elements

__device__ __forceinline__ unsigned short f2bf(float f) {
    unsigned int u = __float_as_uint(f);
    unsigned int r = (u + 0x7FFFu + ((u >> 16) & 1u)) >> 16;
    return (unsigned short)r;
}

#define GLDS16(g, l) __builtin_amdgcn_global_load_lds( \
    (const __attribute__((address_space(1))) unsigned int*)(g), \
    (__attribute__((address_space(3))) unsigned int*)(l), 16, 0, 0)

// ---------------- cast f32 -> bf16 into workspace ----------------
__global__ void cast_all(const float* __restrict__ x,
                         const float* __restrict__ wqkv,
                         const float* __restrict__ wproj,
                         unsigned short* __restrict__ dst) {
    const int T1 = 12582912;       // x
    const int T2 = T1 + 1769472;   // + w_qkv
    const int T3 = T2 + 589824;    // + w_proj
    int stride = gridDim.x * blockDim.x * 4;
    for (int base = (blockIdx.x * blockDim.x + threadIdx.x) * 4; base < T3; base += stride) {
        const float* src; int off;
        if (base < T1)      { src = x;     off = base; }
        else if (base < T2) { src = wqkv;  off = base - T1; }
        else                { src = wproj; off = base - T2; }
        float4 v = *(const float4*)(src + off);
        ushort4 o;
        o.x = f2bf(v.x); o.y = f2bf(v.y); o.z = f2bf(v.z); o.w = f2bf(v.w);
        *(ushort4*)(dst + base) = o;
    }
}

// ---------------- big GEMM: 256x128 tile, BK=32, 8 waves, 3-deep pipeline ----------------
// A: [M][768] bf16 row-major. Bw: [Nw][768] bf16 row-major (B^T input).
// MODE 0: qkv epilogue (scatter f32 to d_out q/k/v blocks). MODE 1: proj epilogue (+bias, f32 row-major).
// LDS per buffer: A 256x32 bf16 = 16KB, B 128x32 bf16 = 8KB -> 24KB; x3 ring = 72KB.
// Swizzle: phys (row, pb) holds logical col-byte (pb ^ ((row&3)<<4)) -> wave64 ds_read_b128 bank-uniform.
template <int MODE>
__global__ __launch_bounds__(512, 2) void gemm_big(const unsigned short* __restrict__ A,
                                                   const unsigned short* __restrict__ Bw,
                                                   const float* __restrict__ bias,
                                                   float* __restrict__ dout,
                                                   int nby) {
    __shared__ unsigned char lds8[73728];
    const int t = threadIdx.x;
    const int lane = t & 63;
    const int w = t >> 6;
    const int wm = w >> 1, wn = w & 1;   // 4m x 2n waves, 64x64 tile each

    // bijective XCD chunk swizzle (grid sizes here are % 8 == 0)
    const int cpx = gridDim.x >> 3;
    const int orig = blockIdx.x;
    const int wgid = (orig & 7) * cpx + (orig >> 3);
    const int bx = wgid / nby, by = wgid - bx * nby;  // by fastest within chunk
    const int m0 = bx * 256;
    const int n0 = by * 128;

    const unsigned char* Ab = (const unsigned char*)A;
    const unsigned char* Bb = (const unsigned char*)Bw;

    // stage source offsets (bytes), inverse-swizzled so linear LDS dest = swizzled layout
    size_t aSrc0, aSrc1, bSrc;
    {
        int c0 = t, c1 = 512 + t;
        int r0 = c0 >> 2, p0 = (c0 & 3) << 4;
        int r1 = c1 >> 2, p1 = (c1 & 3) << 4;
        aSrc0 = (size_t)(m0 + r0) * 1536 + (p0 ^ ((r0 & 3) << 4));
        aSrc1 = (size_t)(m0 + r1) * 1536 + (p1 ^ ((r1 & 3) << 4));
        int rb = t >> 2, pb = (t & 3) << 4;
        bSrc  = (size_t)(n0 + rb) * 1536 + (pb ^ ((rb & 3) << 4));
    }

    // fragment read offsets (swizzled phys addr), loop-invariant
    int aOff[4], bOff[4];
#pragma unroll
    for (int mi = 0; mi < 4; ++mi) {
        int row = wm * 64 + mi * 16 + (lane & 15);
        aOff[mi] = row * 64 + ((((lane >> 4) << 4)) ^ ((row & 3) << 4));
    }
#pragma unroll
    for (int ni = 0; ni < 4; ++ni) {
        int row = wn * 64 + ni * 16 + (lane & 15);
        bOff[ni] = 16384 + row * 64 + ((((lane >> 4) << 4)) ^ ((row & 3) << 4));
    }

    f32x4 acc[4][4] = {};

#define STAGE(bi, kt) do { \
    unsigned char* dst_ = lds8 + (bi) * 24576; \
    GLDS16(Ab + aSrc0 + (size_t)(kt) * 64, dst_ + t * 16); \
    GLDS16(Ab + aSrc1 + (size_t)(kt) * 64, dst_ + 8192 + t * 16); \
    GLDS16(Bb + bSrc  + (size_t)(kt) * 64, dst_ + 16384 + t * 16); \
} while (0)

    STAGE(0, 0);
    STAGE(1, 1);
    int bi = 0;
    for (int kt = 0; kt < 24; ++kt) {
        if (kt < 22) {
            int si = bi + 2; if (si >= 3) si -= 3;
            STAGE(si, kt + 2);
            asm volatile("s_waitcnt vmcnt(6)" ::: "memory");   // tile kt's 3 loads done; 6 in flight
        } else if (kt == 22) {
            asm volatile("s_waitcnt vmcnt(3)" ::: "memory");
        } else {
            asm volatile("s_waitcnt vmcnt(0)" ::: "memory");
        }
        __builtin_amdgcn_s_barrier();
        asm volatile("" ::: "memory");
        const unsigned char* base = lds8 + bi * 24576;
        bf16x8 av[4], bv[4];
#pragma unroll
        for (int mi = 0; mi < 4; ++mi) av[mi] = *(const bf16x8*)(base + aOff[mi]);
#pragma unroll
        for (int ni = 0; ni < 4; ++ni) bv[ni] = *(const bf16x8*)(base + bOff[ni]);
#pragma unroll
        for (int mi = 0; mi < 4; ++mi)
#pragma unroll
            for (int ni = 0; ni < 4; ++ni)
                acc[mi][ni] = __builtin_amdgcn_mfma_f32_16x16x32_bf16(av[mi], bv[ni], acc[mi][ni], 0, 0, 0);
        // drain our ds_reads before the barrier: next iter's STAGE (other waves) overwrites this buffer
        asm volatile("s_waitcnt lgkmcnt(0)" ::: "memory");
        __builtin_amdgcn_s_barrier();
        asm volatile("" ::: "memory");
        ++bi; if (bi == 3) bi = 0;
    }
#undef STAGE

    const int crow = (lane >> 4) * 4;  // C row (+reg r)
    const int ccol = lane & 15;        // C col
    if (MODE == 0) {
        const int b = m0 >> 12;        // batch (m-tiles align with 4096 boundary)
        const int n_base = m0 & 4095;
#pragma unroll
        for (int mi = 0; mi < 4; ++mi) {
            int n = n_base + wm * 64 + mi * 16 + crow;  // 4 consecutive n (regs)
#pragma unroll
            for (int ni = 0; ni < 4; ++ni) {
                int o = n0 + wn * 64 + ni * 16 + ccol;  // column in [0,2304)
                int sel = o / 768;                      // 0=q 1=k 2=v
                int rem = o - sel * 768;                // dil*256 + c'
                float* dst = dout + (size_t)(3 - sel) * SZQKV
                           + ((size_t)((rem >> 8) * 4 + b) * 256 + (rem & 255)) * 4096 + n;
                *(f32x4*)dst = acc[mi][ni];
            }
        }
    } else {
#pragma unroll
        for (int mi = 0; mi < 4; ++mi) {
            int m = m0 + wm * 64 + mi * 16 + crow;
#pragma unroll
            for (int ni = 0; ni < 4; ++ni) {
                int o = n0 + wn * 64 + ni * 16 + ccol;
                float bb = bias[o];
#pragma unroll
                for (int r = 0; r < 4; ++r)
                    dout[(size_t)(m + r) * 768 + o] = acc[mi][ni][r] + bb;
            }
        }
    }
}

// ---------------- attention: read q/k/v f32 from d_out, write bf16 [b][n][c] ----------------
__global__ __launch_bounds__(256) void attn_kernel(const float* __restrict__ qkv,
                                                   unsigned short* __restrict__ attnbf) {
    const int chunk = blockIdx.x;  // 64 chunks of 64 n
    const int dil_i = blockIdx.y;  // 0..2
    const int b     = blockIdx.z;  // 0..3
    const int dil   = dil_i + 1;
    const int t  = threadIdx.x;
    const int h  = t >> 6;         // wave = head
    const int nl = t & 63;
    const int n  = chunk * 64 + nl;

    const size_t gb = (size_t)(dil_i * 4 + b) * 256 * 4096;
    const float* Q = qkv + (size_t)3 * SZQKV + gb;
    const float* K = qkv + (size_t)2 * SZQKV + gb;
    const float* V = qkv + (size_t)1 * SZQKV + gb;

    const int nm = n - dil, np = n + dil;
    const bool vm = (nm >= 0), vp = (np < 4096);
    const int nmc = vm ? nm : 0, npc = vp ? np : 4095;

    float s0 = 0.f, s1 = 0.f, s2 = 0.f;
    {
        const float* qrow = Q + (size_t)h * 64 * 4096;
        const float* krow = K + (size_t)h * 64 * 4096;
        for (int d = 0; d < 64; ++d) {
            float q = qrow[n];
            s0 += q * krow[nmc];
            s1 += q * krow[n];
            s2 += q * krow[npc];
            qrow += 4096; krow += 4096;
        }
    }
    s0 = vm ? s0 * 0.125f : 0.f;   // padded K-column -> exact 0 score (matches ref)
    s1 *= 0.125f;
    s2 = vp ? s2 * 0.125f : 0.f;
    float mx = fmaxf(0.f, fmaxf(s0, fmaxf(s1, s2)));
    float e0 = __expf(s0 - mx), e1 = __expf(s1 - mx), e2 = __expf(s2 - mx);
    // softmax over 9 slots: 6 structural zeros contribute 6*exp(-mx)
    float den = e0 + e1 + e2 + 6.f * __expf(-mx);
    float inv = 1.f / den;
    float p0 = vm ? e0 * inv : 0.f;
    float p1 = e1 * inv;
    float p2 = vp ? e2 * inv : 0.f;

    __shared__ unsigned short lout[256][65];  // [c'][n] bf16, padded row
    {
        const float* vrow = V + (size_t)h * 64 * 4096;
        for (int d = 0; d < 64; ++d) {
            float o = p0 * vrow[nmc] + p1 * vrow[n] + p2 * vrow[npc];
            lout[h * 64 + d][nl] = f2bf(o);
            vrow += 4096;
        }
    }
    __syncthreads();

    // write tile transposed: attnbf[(b*4096+n)*768 + dil_i*256 + c], c fastest
#pragma unroll
    for (int i = 0; i < 8; ++i) {
        int linear = i * 256 + t;   // 0..2047
        int nn   = linear >> 5;     // 0..63
        int cblk = linear & 31;     // 0..31 (8 channels each)
        union { unsigned short u[8]; f32x4 v; } tt;
#pragma unroll
        for (int j = 0; j < 8; ++j) tt.u[j] = lout[cblk * 8 + j][nn];
        unsigned short* dst = attnbf + (size_t)(b * 4096 + chunk * 64 + nn) * 768
                            + dil_i * 256 + cblk * 8;
        *(f32x4*)dst = tt.v;
    }
}

extern "C" void kernel_launch(void* const* d_in, const int* in_sizes, int n_in,
                              void* d_out, int out_size, void* d_ws, size_t ws_size,
                              hipStream_t stream) {
    const float* x     = (const float*)d_in[0];
    const float* wqkv  = (const float*)d_in[1];
    const float* wproj = (const float*)d_in[2];
    const float* bproj = (const float*)d_in[3];
    float* out = (float*)d_out;

    unsigned short* xbf     = (unsigned short*)d_ws;          // 12582912
    unsigned short* wqkvbf  = xbf + 12582912;                 // 1769472
    unsigned short* wprojbf = wqkvbf + 1769472;               // 589824
    unsigned short* attnbf  = wprojbf + 589824;               // 12582912

    cast_all<<<2048, 256, 0, stream>>>(x, wqkv, wproj, xbf);

    // qkv: M=16384, Nw=2304 -> grid 64 x 18 = 1152 (%8==0)
    gemm_big<0><<<dim3(64 * 18), 512, 0, stream>>>(xbf, wqkvbf, nullptr, out, 18);

    attn_kernel<<<dim3(64, 3, 4), 256, 0, stream>>>(out, attnbf);

    // proj: M=16384, Nw=768 -> grid 64 x 6 = 384 (%8==0)
    gemm_big<1><<<dim3(64 * 6), 512, 0, stream>>>(attnbf, wprojbf, bproj, out, 6);
}